// Round 10
// baseline (639.699 us; speedup 1.0000x reference)
//
#include <hip/hip_runtime.h>

#define NUSERS  200000
#define NMOVIES 200000
#define NROWS   200000
#define NROWS3  (3 * NROWS)
#define NBLK    ((NROWS + 255) / 256)   // 782 scan blocks per array
#define EDGE_GRID 2048

typedef __attribute__((ext_vector_type(8))) short bf16x8;
typedef __attribute__((ext_vector_type(4))) float f32x4;

// ---------------------------------------------------------------------------
// K1: histogram + within-bucket slot. Thread per edge.
// ---------------------------------------------------------------------------
__global__ __launch_bounds__(256) void hist_kernel(
    const int* __restrict__ um, const int* __restrict__ me,
    int* __restrict__ cnt_u, int* __restrict__ cnt_m, int* __restrict__ cnt_e,
    int2* __restrict__ w_um, int* __restrict__ w_me,
    int E_um, int E_me)
{
    const int total = E_um + E_me;
    for (int t = blockIdx.x * blockDim.x + threadIdx.x; t < total;
         t += gridDim.x * blockDim.x) {
        if (t < E_um) {
            const int a = um[t];
            const int b = um[E_um + t];
            int2 w;
            w.x = atomicAdd(&cnt_u[a], 1);
            w.y = atomicAdd(&cnt_m[b], 1);
            w_um[t] = w;
        } else {
            const int e = t - E_um;
            const int d = me[E_me + e];
            w_me[e] = atomicAdd(&cnt_e[d], 1);
        }
    }
}

// ---------------------------------------------------------------------------
// K2a: block-local exclusive scan of the 3 cnt arrays (256/block).
// ---------------------------------------------------------------------------
__global__ __launch_bounds__(256) void scan_blocks_kernel(
    const int* __restrict__ cnt_all,   // [3][NROWS]
    int* __restrict__ sl_all,          // [3][NROWS]
    int* __restrict__ bsum)            // [3][1024]
{
    __shared__ int tmp[256];
    const int tid = threadIdx.x;
    const int arr = blockIdx.x / NBLK;
    const int blk = blockIdx.x % NBLK;
    const int idx = blk * 256 + tid;
    const int val = (idx < NROWS) ? cnt_all[arr * NROWS + idx] : 0;
    tmp[tid] = val;
    __syncthreads();
#pragma unroll
    for (int off = 1; off < 256; off <<= 1) {
        const int t = (tid >= off) ? tmp[tid - off] : 0;
        __syncthreads();
        tmp[tid] += t;
        __syncthreads();
    }
    const int incl = tmp[tid];
    if (idx < NROWS) sl_all[arr * NROWS + idx] = incl - val;
    if (tid == 255) bsum[arr * 1024 + blk] = incl;
}

// ---------------------------------------------------------------------------
// K2b: single-block scan of block sums (NBLK=782 <= 1024 -> one pass/array).
// ---------------------------------------------------------------------------
__global__ __launch_bounds__(1024) void scan_tops_kernel(
    const int* __restrict__ bsum,      // [3][1024]
    int* __restrict__ bo_all)          // [3][1024]
{
    __shared__ int tmp[1024];
    const int tid = threadIdx.x;
    for (int arr = 0; arr < 3; ++arr) {
        const int val = (tid < NBLK) ? bsum[arr * 1024 + tid] : 0;
        tmp[tid] = val;
        __syncthreads();
#pragma unroll
        for (int off = 1; off < 1024; off <<= 1) {
            const int t = (tid >= off) ? tmp[tid - off] : 0;
            __syncthreads();
            tmp[tid] += t;
            __syncthreads();
        }
        if (tid < NBLK) bo_all[arr * 1024 + tid] = tmp[tid] - val;
        __syncthreads();
    }
}

// ---------------------------------------------------------------------------
// K3: scatter src ids into dense buckets (no atomics). NT stores to avoid
// write-allocate line round-trips on the random 4B stores.
// ---------------------------------------------------------------------------
__global__ __launch_bounds__(256) void scatter_kernel(
    const int* __restrict__ um, const int* __restrict__ me,
    const int* __restrict__ sl_all, const int* __restrict__ bo_all,
    const int2* __restrict__ w_um, const int* __restrict__ w_me,
    int* __restrict__ bk_u, int* __restrict__ bk_m, int* __restrict__ bk_e,
    int E_um, int E_me)
{
    const int* sl_u = sl_all;
    const int* sl_m = sl_all + NROWS;
    const int* sl_e = sl_all + 2 * NROWS;
    const int* bo_u = bo_all;
    const int* bo_m = bo_all + 1024;
    const int* bo_e = bo_all + 2048;
    const int total = E_um + E_me;
    for (int t = blockIdx.x * blockDim.x + threadIdx.x; t < total;
         t += gridDim.x * blockDim.x) {
        if (t < E_um) {
            const int a = um[t];
            const int b = um[E_um + t];
            const int2 w = w_um[t];
            __builtin_nontemporal_store(b, &bk_u[sl_u[a] + bo_u[a >> 8] + w.x]);
            __builtin_nontemporal_store(a, &bk_m[sl_m[b] + bo_m[b >> 8] + w.y]);
        } else {
            const int e = t - E_um;
            const int s = me[e];
            const int d = me[E_me + e];
            __builtin_nontemporal_store(s, &bk_e[sl_e[d] + bo_e[d >> 8] + w_me[e]]);
        }
    }
}

// ---------------------------------------------------------------------------
// Prep: split W_cat = [W1;W2;Wrel;Wroot] (256x64) into bf16 hi/lo,
// pre-swizzled for the fragment mapping
//   frag f = (s*4 + t)*64 + lane, elem j:  k = 32s + 8*(lane>>4) + j,
//   col = 16t + (lane&15)
// ---------------------------------------------------------------------------
__global__ __launch_bounds__(256) void bsplit_kernel(
    const float* __restrict__ W1, const float* __restrict__ W2,
    const float* __restrict__ Wrel, const float* __restrict__ Wroot,
    unsigned short* __restrict__ BH, unsigned short* __restrict__ BL)
{
    const int idx = blockIdx.x * blockDim.x + threadIdx.x;
    if (idx >= 8 * 4 * 64 * 8) return;
    const int j = idx & 7;
    const int f = idx >> 3;
    const int l = f & 63;
    const int t = (f >> 6) & 3;
    const int s = f >> 8;
    const int k = 32 * s + 8 * (l >> 4) + j;
    const int col = 16 * t + (l & 15);
    const float* Wsrc;
    switch (k >> 6) {
        case 0:  Wsrc = W1;    break;
        case 1:  Wsrc = W2;    break;
        case 2:  Wsrc = Wrel;  break;
        default: Wsrc = Wroot; break;
    }
    const float v = Wsrc[(k & 63) * 64 + col];
    const unsigned int bits = __float_as_uint(v);
    const unsigned short h = (unsigned short)(bits >> 16);
    const float rem = v - __uint_as_float((unsigned)h << 16);
    BH[idx] = h;
    BL[idx] = (unsigned short)(__float_as_uint(rem) >> 16);
}

// ---- bf16x3 split helpers ----
__device__ __forceinline__ short bf_hi(float v, float& rem) {
    const unsigned int b = __float_as_uint(v);
    const unsigned short h = (unsigned short)(b >> 16);
    rem = v - __uint_as_float((unsigned)h << 16);
    return (short)h;
}
__device__ __forceinline__ short bf_tr(float v) {
    return (short)(__float_as_uint(v) >> 16);
}
__device__ __forceinline__ void split8v(const float q[8],
                                        bf16x8& Ah, bf16x8& Al) {
    float r[8];
#pragma unroll
    for (int j = 0; j < 8; ++j) Ah[j] = bf_hi(q[j], r[j]);
#pragma unroll
    for (int j = 0; j < 8; ++j) Al[j] = bf_tr(r[j]);
}

#define MFMA3(acc, Ah, Al, Bh, Bl)                                           \
    acc = __builtin_amdgcn_mfma_f32_16x16x32_bf16(Ah, Bh, acc, 0, 0, 0);     \
    acc = __builtin_amdgcn_mfma_f32_16x16x32_bf16(Al, Bh, acc, 0, 0, 0);     \
    acc = __builtin_amdgcn_mfma_f32_16x16x32_bf16(Ah, Bl, acc, 0, 0, 0);

// ---------------------------------------------------------------------------
// Fused gather + finalize, users. Block = 4 waves; wave owns 16 rows.
// Phase 1: wave gathers S1 rows into transposed per-wave LDS tile [64ch][17].
// Phase 2: MFMA [S1, x.S1] @ [W1;W2] (bf16x3) + cnt*(b1+b2); x-copy.
// ---------------------------------------------------------------------------
__global__ __launch_bounds__(256) void fuse_user_kernel(
    const float* __restrict__ user_x,
    const int* __restrict__ bk_u,
    const int* __restrict__ cnt_u,
    const int* __restrict__ sl_u, const int* __restrict__ bo_u,
    const float* __restrict__ b1, const float* __restrict__ b2,
    const unsigned short* __restrict__ BH,
    const unsigned short* __restrict__ BL,
    float* __restrict__ out_user)
{
    __shared__ float tS1[4][64][17];
    const int lane = threadIdx.x & 63;
    const int wv = threadIdx.x >> 6;
    const int sub = lane & 15, grp = lane >> 4;
    const int rbase = blockIdx.x * 64 + wv * 16;
    const int myrow = rbase + sub;

    // ---- gather S1 for 16 rows (lane = channel), transpose into LDS ----
    for (int i = 0; i < 16; ++i) {
        const int r = rbase + i;
        const int c = cnt_u[r];
        const int base = sl_u[r] + bo_u[r >> 8];
        float a0 = 0.f, a1 = 0.f, a2 = 0.f, a3 = 0.f;
        int j = 0;
        for (; j + 4 <= c; j += 4) {
            const int s0 = bk_u[base + j];
            const int s1 = bk_u[base + j + 1];
            const int s2 = bk_u[base + j + 2];
            const int s3 = bk_u[base + j + 3];
            a0 += user_x[(size_t)s0 * 64 + lane];
            a1 += user_x[(size_t)s1 * 64 + lane];
            a2 += user_x[(size_t)s2 * 64 + lane];
            a3 += user_x[(size_t)s3 * 64 + lane];
        }
        for (; j < c; ++j) a0 += user_x[(size_t)bk_u[base + j] * 64 + lane];
        tS1[wv][lane][i] = (a0 + a1) + (a2 + a3);
    }
    // wave-private tile: no barrier needed (in-wave LDS ordering via waitcnt)

    f32x4 acc0 = {0.f, 0.f, 0.f, 0.f}, acc1 = acc0, acc2 = acc0, acc3 = acc0;

#pragma unroll
    for (int s = 0; s < 4; ++s) {
        const int ch0 = 32 * (s & 1) + 8 * grp;
        float q[8];
#pragma unroll
        for (int j = 0; j < 8; ++j) q[j] = tS1[wv][ch0 + j][sub];
        if (s >= 2) {
            const float* px = user_x + (size_t)myrow * 64 + ch0;
            const float4 x0 = *(const float4*)px;
            const float4 x1 = *(const float4*)(px + 4);
            q[0] *= x0.x; q[1] *= x0.y; q[2] *= x0.z; q[3] *= x0.w;
            q[4] *= x1.x; q[5] *= x1.y; q[6] *= x1.z; q[7] *= x1.w;
        }
        bf16x8 Ah, Al;
        split8v(q, Ah, Al);
#pragma unroll
        for (int t = 0; t < 4; ++t) {
            const int fo = ((s * 4 + t) * 64 + lane) * 8;
            const bf16x8 Bh = *(const bf16x8*)(BH + fo);
            const bf16x8 Bl = *(const bf16x8*)(BL + fo);
            if (t == 0) { MFMA3(acc0, Ah, Al, Bh, Bl) }
            else if (t == 1) { MFMA3(acc1, Ah, Al, Bh, Bl) }
            else if (t == 2) { MFMA3(acc2, Ah, Al, Bh, Bl) }
            else { MFMA3(acc3, Ah, Al, Bh, Bl) }
        }
    }

    // x-copy
#pragma unroll
    for (int i = 0; i < 4; ++i) {
        const int row = rbase + 4 * i + grp;
        const float4 xv = *(const float4*)(user_x + (size_t)row * 64 + sub * 4);
        *(float4*)(out_user + (size_t)row * 128 + sub * 4) = xv;
    }

    // epilogue: C/D layout col = lane&15, row = 4*(lane>>4) + reg
#pragma unroll
    for (int t = 0; t < 4; ++t) {
        const int col = 16 * t + sub;
        const float bb = b1[col] + b2[col];
        const f32x4 a = (t == 0) ? acc0 : (t == 1) ? acc1 : (t == 2) ? acc2 : acc3;
#pragma unroll
        for (int r = 0; r < 4; ++r) {
            const int row = rbase + 4 * grp + r;
            out_user[(size_t)row * 128 + 64 + col] =
                a[r] + (float)cnt_u[row] * bb;
        }
    }
}

// ---------------------------------------------------------------------------
// Fused gather + finalize, movies. Gathers S1m (bk_m/movie_x) and Se
// (bk_e/entity_x) into two LDS tiles, then K=256 MFMA:
//   [S1, x.S1, Se/ce, ex] @ [W1;W2;Wrel;Wroot] + cnt*(b1+b2) + brgcn
// ---------------------------------------------------------------------------
__global__ __launch_bounds__(256) void fuse_movie_kernel(
    const float* __restrict__ movie_x,
    const float* __restrict__ entity_x,
    const int* __restrict__ bk_m, const int* __restrict__ bk_e,
    const int* __restrict__ cnt_m, const int* __restrict__ cnt_e,
    const int* __restrict__ sl_m, const int* __restrict__ bo_m,
    const int* __restrict__ sl_e, const int* __restrict__ bo_e,
    const float* __restrict__ b1, const float* __restrict__ b2,
    const float* __restrict__ brgcn,
    const unsigned short* __restrict__ BH,
    const unsigned short* __restrict__ BL,
    float* __restrict__ out_movie)
{
    __shared__ float tS1[4][64][17];
    __shared__ float tSe[4][64][17];
    const int lane = threadIdx.x & 63;
    const int wv = threadIdx.x >> 6;
    const int sub = lane & 15, grp = lane >> 4;
    const int rbase = blockIdx.x * 64 + wv * 16;
    const int myrow = rbase + sub;

    for (int i = 0; i < 16; ++i) {
        const int r = rbase + i;
        {
            const int c = cnt_m[r];
            const int base = sl_m[r] + bo_m[r >> 8];
            float a0 = 0.f, a1 = 0.f, a2 = 0.f, a3 = 0.f;
            int j = 0;
            for (; j + 4 <= c; j += 4) {
                const int s0 = bk_m[base + j];
                const int s1 = bk_m[base + j + 1];
                const int s2 = bk_m[base + j + 2];
                const int s3 = bk_m[base + j + 3];
                a0 += movie_x[(size_t)s0 * 64 + lane];
                a1 += movie_x[(size_t)s1 * 64 + lane];
                a2 += movie_x[(size_t)s2 * 64 + lane];
                a3 += movie_x[(size_t)s3 * 64 + lane];
            }
            for (; j < c; ++j) a0 += movie_x[(size_t)bk_m[base + j] * 64 + lane];
            tS1[wv][lane][i] = (a0 + a1) + (a2 + a3);
        }
        {
            const int c = cnt_e[r];
            const int base = sl_e[r] + bo_e[r >> 8];
            float a0 = 0.f, a1 = 0.f, a2 = 0.f, a3 = 0.f;
            int j = 0;
            for (; j + 4 <= c; j += 4) {
                const int s0 = bk_e[base + j];
                const int s1 = bk_e[base + j + 1];
                const int s2 = bk_e[base + j + 2];
                const int s3 = bk_e[base + j + 3];
                a0 += entity_x[(size_t)s0 * 64 + lane];
                a1 += entity_x[(size_t)s1 * 64 + lane];
                a2 += entity_x[(size_t)s2 * 64 + lane];
                a3 += entity_x[(size_t)s3 * 64 + lane];
            }
            for (; j < c; ++j) a0 += entity_x[(size_t)bk_e[base + j] * 64 + lane];
            tSe[wv][lane][i] = (a0 + a1) + (a2 + a3);
        }
    }

    const float invce = 1.0f / fmaxf((float)cnt_e[myrow], 1.0f);

    f32x4 acc0 = {0.f, 0.f, 0.f, 0.f}, acc1 = acc0, acc2 = acc0, acc3 = acc0;

#pragma unroll
    for (int s = 0; s < 8; ++s) {
        float q[8];
        if (s < 4) {
            const int ch0 = 32 * (s & 1) + 8 * grp;
#pragma unroll
            for (int j = 0; j < 8; ++j) q[j] = tS1[wv][ch0 + j][sub];
            if (s >= 2) {
                const float* px = movie_x + (size_t)myrow * 64 + ch0;
                const float4 x0 = *(const float4*)px;
                const float4 x1 = *(const float4*)(px + 4);
                q[0] *= x0.x; q[1] *= x0.y; q[2] *= x0.z; q[3] *= x0.w;
                q[4] *= x1.x; q[5] *= x1.y; q[6] *= x1.z; q[7] *= x1.w;
            }
        } else if (s < 6) {
            const int ch0 = 32 * (s - 4) + 8 * grp;
#pragma unroll
            for (int j = 0; j < 8; ++j) q[j] = tSe[wv][ch0 + j][sub] * invce;
        } else {
            const int ch0 = 32 * (s - 6) + 8 * grp;
            const float* p = entity_x + (size_t)myrow * 64 + ch0;
            const float4 e0 = *(const float4*)p;
            const float4 e1 = *(const float4*)(p + 4);
            q[0] = e0.x; q[1] = e0.y; q[2] = e0.z; q[3] = e0.w;
            q[4] = e1.x; q[5] = e1.y; q[6] = e1.z; q[7] = e1.w;
        }
        bf16x8 Ah, Al;
        split8v(q, Ah, Al);
#pragma unroll
        for (int t = 0; t < 4; ++t) {
            const int fo = ((s * 4 + t) * 64 + lane) * 8;
            const bf16x8 Bh = *(const bf16x8*)(BH + fo);
            const bf16x8 Bl = *(const bf16x8*)(BL + fo);
            if (t == 0) { MFMA3(acc0, Ah, Al, Bh, Bl) }
            else if (t == 1) { MFMA3(acc1, Ah, Al, Bh, Bl) }
            else if (t == 2) { MFMA3(acc2, Ah, Al, Bh, Bl) }
            else { MFMA3(acc3, Ah, Al, Bh, Bl) }
        }
    }

#pragma unroll
    for (int i = 0; i < 4; ++i) {
        const int row = rbase + 4 * i + grp;
        const float4 xv = *(const float4*)(movie_x + (size_t)row * 64 + sub * 4);
        *(float4*)(out_movie + (size_t)row * 128 + sub * 4) = xv;
    }

#pragma unroll
    for (int t = 0; t < 4; ++t) {
        const int col = 16 * t + sub;
        const float bb = b1[col] + b2[col];
        const float br = brgcn[col];
        const f32x4 a = (t == 0) ? acc0 : (t == 1) ? acc1 : (t == 2) ? acc2 : acc3;
#pragma unroll
        for (int r = 0; r < 4; ++r) {
            const int row = rbase + 4 * grp + r;
            out_movie[(size_t)row * 128 + 64 + col] =
                a[r] + (float)cnt_m[row] * bb + br;
        }
    }
}

extern "C" void kernel_launch(void* const* d_in, const int* in_sizes, int n_in,
                              void* d_out, int out_size, void* d_ws, size_t ws_size,
                              hipStream_t stream)
{
    const float* user_x   = (const float*)d_in[0];
    const float* movie_x  = (const float*)d_in[1];
    const float* entity_x = (const float*)d_in[2];
    const int*   um       = (const int*)d_in[3];
    const int*   me       = (const int*)d_in[4];
    const float* W1       = (const float*)d_in[5];
    const float* b1       = (const float*)d_in[6];
    const float* W2       = (const float*)d_in[7];
    const float* b2       = (const float*)d_in[8];
    const float* Wrel     = (const float*)d_in[9];
    const float* Wroot    = (const float*)d_in[10];
    const float* brgcn    = (const float*)d_in[11];

    const int E_um = in_sizes[3] / 2;
    const int E_me = in_sizes[4] / 2;

    float* out_user  = (float*)d_out;                         // [NUSERS, 128]
    float* out_movie = out_user + (size_t)NUSERS * 128;       // [NMOVIES, 128]

    // Workspace layout (ints)
    int* cnt_all = (int*)d_ws;                 // [3][NROWS]  - zeroed
    int* sl_all  = cnt_all + NROWS3;           // [3][NROWS]
    int* bsum    = sl_all + NROWS3;            // [3][1024]
    int* bo_all  = bsum + 3 * 1024;            // [3][1024]
    int2* w_um   = (int2*)(bo_all + 3 * 1024); // [E_um] (int2)
    int* w_me    = (int*)(w_um + E_um);        // [E_me]
    int* bk_u    = w_me + E_me;                // [E_um]
    int* bk_m    = bk_u + E_um;                // [E_um]
    int* bk_e    = bk_m + E_um;                // [E_me]
    uintptr_t bp = (uintptr_t)(bk_e + E_me);
    bp = (bp + 63) & ~(uintptr_t)63;
    unsigned short* BH = (unsigned short*)bp;  // [16384]
    unsigned short* BL = BH + 16384;           // [16384]

    int* cnt_u = cnt_all;
    int* cnt_m = cnt_all + NROWS;
    int* cnt_e = cnt_all + 2 * NROWS;

    // Zero the histogram tables (2.4 MB).
    hipMemsetAsync(cnt_all, 0, NROWS3 * sizeof(int), stream);

    bsplit_kernel<<<64, 256, 0, stream>>>(W1, W2, Wrel, Wroot, BH, BL);
    hist_kernel<<<EDGE_GRID, 256, 0, stream>>>(um, me, cnt_u, cnt_m, cnt_e,
                                               w_um, w_me, E_um, E_me);
    scan_blocks_kernel<<<3 * NBLK, 256, 0, stream>>>(cnt_all, sl_all, bsum);
    scan_tops_kernel<<<1, 1024, 0, stream>>>(bsum, bo_all);
    scatter_kernel<<<EDGE_GRID, 256, 0, stream>>>(um, me, sl_all, bo_all,
                                                  w_um, w_me,
                                                  bk_u, bk_m, bk_e, E_um, E_me);

    fuse_user_kernel<<<NUSERS / 64, 256, 0, stream>>>(
        user_x, bk_u, cnt_u, sl_all, bo_all, b1, b2, BH, BL, out_user);
    fuse_movie_kernel<<<NMOVIES / 64, 256, 0, stream>>>(
        movie_x, entity_x, bk_m, bk_e, cnt_m, cnt_e,
        sl_all + NROWS, bo_all + 1024, sl_all + 2 * NROWS, bo_all + 2048,
        b1, b2, brgcn, BH, BL, out_movie);
}

// Round 11
// 518.209 us; speedup vs baseline: 1.2344x; 1.2344x over previous
//
#include <hip/hip_runtime.h>

#define NUSERS  200000
#define NMOVIES 200000
#define NROWS   200000
#define NROWS3  (3 * NROWS)
#define NBLK    ((NROWS + 255) / 256)   // 782 scan blocks per array

typedef __attribute__((ext_vector_type(8))) short bf16x8;
typedef __attribute__((ext_vector_type(4))) float f32x4;

// ---------------------------------------------------------------------------
// K1: histogram, ONE TASK PER THREAD (no serial atomic chains).
//  task t < E_um:          user-side:  w_umu[t] = cnt_u[um0[t]]++
//  E_um <= t < 2E_um:      movie-side: w_umm[e] = cnt_m[um1[e]]++
//  else:                   me-side:    w_me[e]  = cnt_e[me1[e]]++
// ---------------------------------------------------------------------------
__global__ __launch_bounds__(256) void hist_kernel(
    const int* __restrict__ um, const int* __restrict__ me,
    int* __restrict__ cnt_u, int* __restrict__ cnt_m, int* __restrict__ cnt_e,
    int* __restrict__ w_umu, int* __restrict__ w_umm, int* __restrict__ w_me,
    int E_um, int E_me)
{
    const int t = blockIdx.x * blockDim.x + threadIdx.x;
    if (t < E_um) {
        w_umu[t] = atomicAdd(&cnt_u[um[t]], 1);
    } else if (t < 2 * E_um) {
        const int e = t - E_um;
        w_umm[e] = atomicAdd(&cnt_m[um[E_um + e]], 1);
    } else if (t < 2 * E_um + E_me) {
        const int e = t - 2 * E_um;
        w_me[e] = atomicAdd(&cnt_e[me[E_me + e]], 1);
    }
}

// ---------------------------------------------------------------------------
// K2a: block-local exclusive scan of the 3 cnt arrays (256/block).
// ---------------------------------------------------------------------------
__global__ __launch_bounds__(256) void scan_blocks_kernel(
    const int* __restrict__ cnt_all,   // [3][NROWS]
    int* __restrict__ sl_all,          // [3][NROWS]
    int* __restrict__ bsum)            // [3][1024]
{
    __shared__ int tmp[256];
    const int tid = threadIdx.x;
    const int arr = blockIdx.x / NBLK;
    const int blk = blockIdx.x % NBLK;
    const int idx = blk * 256 + tid;
    const int val = (idx < NROWS) ? cnt_all[arr * NROWS + idx] : 0;
    tmp[tid] = val;
    __syncthreads();
#pragma unroll
    for (int off = 1; off < 256; off <<= 1) {
        const int t = (tid >= off) ? tmp[tid - off] : 0;
        __syncthreads();
        tmp[tid] += t;
        __syncthreads();
    }
    const int incl = tmp[tid];
    if (idx < NROWS) sl_all[arr * NROWS + idx] = incl - val;
    if (tid == 255) bsum[arr * 1024 + blk] = incl;
}

// ---------------------------------------------------------------------------
// K2b: single-block scan of block sums (NBLK=782 <= 1024 -> one pass/array).
// ---------------------------------------------------------------------------
__global__ __launch_bounds__(1024) void scan_tops_kernel(
    const int* __restrict__ bsum,      // [3][1024]
    int* __restrict__ bo_all)          // [3][1024]
{
    __shared__ int tmp[1024];
    const int tid = threadIdx.x;
    for (int arr = 0; arr < 3; ++arr) {
        const int val = (tid < NBLK) ? bsum[arr * 1024 + tid] : 0;
        tmp[tid] = val;
        __syncthreads();
#pragma unroll
        for (int off = 1; off < 1024; off <<= 1) {
            const int t = (tid >= off) ? tmp[tid - off] : 0;
            __syncthreads();
            tmp[tid] += t;
            __syncthreads();
        }
        if (tid < NBLK) bo_all[arr * 1024 + tid] = tmp[tid] - val;
        __syncthreads();
    }
}

// ---------------------------------------------------------------------------
// K3: scatter, ONE TASK PER THREAD, NT 4B store into dense buckets.
// ---------------------------------------------------------------------------
__global__ __launch_bounds__(256) void scatter_kernel(
    const int* __restrict__ um, const int* __restrict__ me,
    const int* __restrict__ sl_all, const int* __restrict__ bo_all,
    const int* __restrict__ w_umu, const int* __restrict__ w_umm,
    const int* __restrict__ w_me,
    int* __restrict__ bk_u, int* __restrict__ bk_m, int* __restrict__ bk_e,
    int E_um, int E_me)
{
    const int t = blockIdx.x * blockDim.x + threadIdx.x;
    if (t < E_um) {
        const int a = um[t];
        const int b = um[E_um + t];
        const int* sl_u = sl_all;
        const int* bo_u = bo_all;
        __builtin_nontemporal_store(b, &bk_u[sl_u[a] + bo_u[a >> 8] + w_umu[t]]);
    } else if (t < 2 * E_um) {
        const int e = t - E_um;
        const int a = um[e];
        const int b = um[E_um + e];
        const int* sl_m = sl_all + NROWS;
        const int* bo_m = bo_all + 1024;
        __builtin_nontemporal_store(a, &bk_m[sl_m[b] + bo_m[b >> 8] + w_umm[e]]);
    } else if (t < 2 * E_um + E_me) {
        const int e = t - 2 * E_um;
        const int s = me[e];
        const int d = me[E_me + e];
        const int* sl_e = sl_all + 2 * NROWS;
        const int* bo_e = bo_all + 2048;
        __builtin_nontemporal_store(s, &bk_e[sl_e[d] + bo_e[d >> 8] + w_me[e]]);
    }
}

// ---------------------------------------------------------------------------
// K4: gather-accumulate. Wave per dst row, lane = channel. Zero atomics.
// ---------------------------------------------------------------------------
__global__ __launch_bounds__(256) void gather_kernel(
    const int* __restrict__ bucket,
    const float* __restrict__ x,
    const int* __restrict__ cnt,
    const int* __restrict__ sl,
    const int* __restrict__ bo,
    float* __restrict__ outbase,   // row stride 128 floats
    int out_off, int nrows)
{
    const int lane = threadIdx.x & 63;
    const int wid = __builtin_amdgcn_readfirstlane(
        (blockIdx.x * blockDim.x + threadIdx.x) >> 6);
    const int nw = (gridDim.x * blockDim.x) >> 6;
    const int rpw = (nrows + nw - 1) / nw;
    const int r0 = wid * rpw;
    const int r1 = min(r0 + rpw, nrows);
    for (int r = r0; r < r1; ++r) {
        const int c = cnt[r];
        const int base = sl[r] + bo[r >> 8];
        float acc0 = 0.f, acc1 = 0.f, acc2 = 0.f, acc3 = 0.f;
        int j = 0;
        for (; j + 4 <= c; j += 4) {
            const int s0 = bucket[base + j];
            const int s1 = bucket[base + j + 1];
            const int s2 = bucket[base + j + 2];
            const int s3 = bucket[base + j + 3];
            acc0 += x[(size_t)s0 * 64 + lane];
            acc1 += x[(size_t)s1 * 64 + lane];
            acc2 += x[(size_t)s2 * 64 + lane];
            acc3 += x[(size_t)s3 * 64 + lane];
        }
        for (; j < c; ++j) {
            const int s0 = bucket[base + j];
            acc0 += x[(size_t)s0 * 64 + lane];
        }
        outbase[(size_t)r * 128 + out_off + lane] = (acc0 + acc1) + (acc2 + acc3);
    }
}

// ---------------------------------------------------------------------------
// Prep: split W_cat = [W1;W2;Wrel;Wroot] (256x64) into bf16 hi/lo,
// pre-swizzled for the fragment mapping
//   frag f = (s*4 + t)*64 + lane, elem j:  k = 32s + 8*(lane>>4) + j,
//   col = 16t + (lane&15)
// ---------------------------------------------------------------------------
__global__ __launch_bounds__(256) void bsplit_kernel(
    const float* __restrict__ W1, const float* __restrict__ W2,
    const float* __restrict__ Wrel, const float* __restrict__ Wroot,
    unsigned short* __restrict__ BH, unsigned short* __restrict__ BL)
{
    const int idx = blockIdx.x * blockDim.x + threadIdx.x;
    if (idx >= 8 * 4 * 64 * 8) return;
    const int j = idx & 7;
    const int f = idx >> 3;
    const int l = f & 63;
    const int t = (f >> 6) & 3;
    const int s = f >> 8;
    const int k = 32 * s + 8 * (l >> 4) + j;
    const int col = 16 * t + (l & 15);
    const float* Wsrc;
    switch (k >> 6) {
        case 0:  Wsrc = W1;    break;
        case 1:  Wsrc = W2;    break;
        case 2:  Wsrc = Wrel;  break;
        default: Wsrc = Wroot; break;
    }
    const float v = Wsrc[(k & 63) * 64 + col];
    const unsigned int bits = __float_as_uint(v);
    const unsigned short h = (unsigned short)(bits >> 16);
    const float rem = v - __uint_as_float((unsigned)h << 16);
    BH[idx] = h;
    BL[idx] = (unsigned short)(__float_as_uint(rem) >> 16);
}

// ---- bf16x3 split helpers ----
__device__ __forceinline__ short bf_hi(float v, float& rem) {
    const unsigned int b = __float_as_uint(v);
    const unsigned short h = (unsigned short)(b >> 16);
    rem = v - __uint_as_float((unsigned)h << 16);
    return (short)h;
}
__device__ __forceinline__ short bf_tr(float v) {
    return (short)(__float_as_uint(v) >> 16);
}
__device__ __forceinline__ void split8(float4 q0, float4 q1,
                                       bf16x8& Ah, bf16x8& Al) {
    float r0, r1, r2, r3, r4, r5, r6, r7;
    Ah[0] = bf_hi(q0.x, r0); Ah[1] = bf_hi(q0.y, r1);
    Ah[2] = bf_hi(q0.z, r2); Ah[3] = bf_hi(q0.w, r3);
    Ah[4] = bf_hi(q1.x, r4); Ah[5] = bf_hi(q1.y, r5);
    Ah[6] = bf_hi(q1.z, r6); Ah[7] = bf_hi(q1.w, r7);
    Al[0] = bf_tr(r0); Al[1] = bf_tr(r1); Al[2] = bf_tr(r2); Al[3] = bf_tr(r3);
    Al[4] = bf_tr(r4); Al[5] = bf_tr(r5); Al[6] = bf_tr(r6); Al[7] = bf_tr(r7);
}

#define MFMA3(acc, Ah, Al, Bh, Bl)                                           \
    acc = __builtin_amdgcn_mfma_f32_16x16x32_bf16(Ah, Bh, acc, 0, 0, 0);     \
    acc = __builtin_amdgcn_mfma_f32_16x16x32_bf16(Al, Bh, acc, 0, 0, 0);     \
    acc = __builtin_amdgcn_mfma_f32_16x16x32_bf16(Ah, Bl, acc, 0, 0, 0);

// ---------------------------------------------------------------------------
// Finalize users via MFMA. Block = 4 waves, 64 rows; wave = 16 rows.
// ---------------------------------------------------------------------------
__global__ __launch_bounds__(256) void finalize_user_mfma(
    const float* __restrict__ user_x,
    const int* __restrict__ cnt_u,
    const float* __restrict__ b1, const float* __restrict__ b2,
    const unsigned short* __restrict__ BH,
    const unsigned short* __restrict__ BL,
    float* out_user)
{
    const int lane = threadIdx.x & 63;
    const int wv = threadIdx.x >> 6;
    const int sub = lane & 15, grp = lane >> 4;
    const int rbase = blockIdx.x * 64 + wv * 16;
    const int myrow = rbase + sub;

    f32x4 acc0 = {0.f, 0.f, 0.f, 0.f}, acc1 = acc0, acc2 = acc0, acc3 = acc0;

#pragma unroll
    for (int s = 0; s < 4; ++s) {
        float4 q0, q1;
        if (s < 2) {
            const float* p = out_user + (size_t)myrow * 128 + 64 + 32 * s + 8 * grp;
            q0 = *(const float4*)p;
            q1 = *(const float4*)(p + 4);
        } else {
            const int off = 32 * (s - 2) + 8 * grp;
            const float* ps = out_user + (size_t)myrow * 128 + 64 + off;
            const float* px = user_x + (size_t)myrow * 64 + off;
            const float4 s0 = *(const float4*)ps, s1 = *(const float4*)(ps + 4);
            const float4 x0 = *(const float4*)px, x1 = *(const float4*)(px + 4);
            q0.x = s0.x * x0.x; q0.y = s0.y * x0.y;
            q0.z = s0.z * x0.z; q0.w = s0.w * x0.w;
            q1.x = s1.x * x1.x; q1.y = s1.y * x1.y;
            q1.z = s1.z * x1.z; q1.w = s1.w * x1.w;
        }
        bf16x8 Ah, Al;
        split8(q0, q1, Ah, Al);
#pragma unroll
        for (int t = 0; t < 4; ++t) {
            const int fo = ((s * 4 + t) * 64 + lane) * 8;
            const bf16x8 Bh = *(const bf16x8*)(BH + fo);
            const bf16x8 Bl = *(const bf16x8*)(BL + fo);
            if (t == 0) { MFMA3(acc0, Ah, Al, Bh, Bl) }
            else if (t == 1) { MFMA3(acc1, Ah, Al, Bh, Bl) }
            else if (t == 2) { MFMA3(acc2, Ah, Al, Bh, Bl) }
            else { MFMA3(acc3, Ah, Al, Bh, Bl) }
        }
    }

#pragma unroll
    for (int i = 0; i < 4; ++i) {
        const int row = rbase + 4 * i + grp;
        const float4 xv = *(const float4*)(user_x + (size_t)row * 64 + sub * 4);
        *(float4*)(out_user + (size_t)row * 128 + sub * 4) = xv;
    }

    // epilogue: C/D layout col = lane&15, row = 4*(lane>>4) + reg
#pragma unroll
    for (int t = 0; t < 4; ++t) {
        const int col = 16 * t + sub;
        const float bb = b1[col] + b2[col];
        const f32x4 a = (t == 0) ? acc0 : (t == 1) ? acc1 : (t == 2) ? acc2 : acc3;
#pragma unroll
        for (int r = 0; r < 4; ++r) {
            const int row = rbase + 4 * grp + r;
            out_user[(size_t)row * 128 + 64 + col] =
                a[r] + (float)cnt_u[row] * bb;
        }
    }
}

// ---------------------------------------------------------------------------
// Finalize movies via MFMA. K=256: [S1, x.S1, Se/ce, ex] @ [W1;W2;Wrel;Wroot]
// ---------------------------------------------------------------------------
__global__ __launch_bounds__(256) void finalize_movie_mfma(
    const float* __restrict__ movie_x,
    const float* __restrict__ entity_x,
    const int* __restrict__ cnt_m, const int* __restrict__ cnt_e,
    const float* __restrict__ b1, const float* __restrict__ b2,
    const float* __restrict__ brgcn,
    const unsigned short* __restrict__ BH,
    const unsigned short* __restrict__ BL,
    float* out_movie)
{
    const int lane = threadIdx.x & 63;
    const int wv = threadIdx.x >> 6;
    const int sub = lane & 15, grp = lane >> 4;
    const int rbase = blockIdx.x * 64 + wv * 16;
    const int myrow = rbase + sub;
    const float invce = 1.0f / fmaxf((float)cnt_e[myrow], 1.0f);

    f32x4 acc0 = {0.f, 0.f, 0.f, 0.f}, acc1 = acc0, acc2 = acc0, acc3 = acc0;

#pragma unroll
    for (int s = 0; s < 8; ++s) {
        float4 q0, q1;
        if (s < 2) {
            const float* p = out_movie + (size_t)myrow * 128 + 64 + 32 * s + 8 * grp;
            q0 = *(const float4*)p;
            q1 = *(const float4*)(p + 4);
        } else if (s < 4) {
            const int off = 32 * (s - 2) + 8 * grp;
            const float* ps = out_movie + (size_t)myrow * 128 + 64 + off;
            const float* px = movie_x + (size_t)myrow * 64 + off;
            const float4 s0 = *(const float4*)ps, s1 = *(const float4*)(ps + 4);
            const float4 x0 = *(const float4*)px, x1 = *(const float4*)(px + 4);
            q0.x = s0.x * x0.x; q0.y = s0.y * x0.y;
            q0.z = s0.z * x0.z; q0.w = s0.w * x0.w;
            q1.x = s1.x * x1.x; q1.y = s1.y * x1.y;
            q1.z = s1.z * x1.z; q1.w = s1.w * x1.w;
        } else if (s < 6) {
            const float* p = out_movie + (size_t)myrow * 128 + 32 * (s - 4) + 8 * grp;
            const float4 e0 = *(const float4*)p, e1 = *(const float4*)(p + 4);
            q0.x = e0.x * invce; q0.y = e0.y * invce;
            q0.z = e0.z * invce; q0.w = e0.w * invce;
            q1.x = e1.x * invce; q1.y = e1.y * invce;
            q1.z = e1.z * invce; q1.w = e1.w * invce;
        } else {
            const float* p = entity_x + (size_t)myrow * 64 + 32 * (s - 6) + 8 * grp;
            q0 = *(const float4*)p;
            q1 = *(const float4*)(p + 4);
        }
        bf16x8 Ah, Al;
        split8(q0, q1, Ah, Al);
#pragma unroll
        for (int t = 0; t < 4; ++t) {
            const int fo = ((s * 4 + t) * 64 + lane) * 8;
            const bf16x8 Bh = *(const bf16x8*)(BH + fo);
            const bf16x8 Bl = *(const bf16x8*)(BL + fo);
            if (t == 0) { MFMA3(acc0, Ah, Al, Bh, Bl) }
            else if (t == 1) { MFMA3(acc1, Ah, Al, Bh, Bl) }
            else if (t == 2) { MFMA3(acc2, Ah, Al, Bh, Bl) }
            else { MFMA3(acc3, Ah, Al, Bh, Bl) }
        }
    }

#pragma unroll
    for (int i = 0; i < 4; ++i) {
        const int row = rbase + 4 * i + grp;
        const float4 xv = *(const float4*)(movie_x + (size_t)row * 64 + sub * 4);
        *(float4*)(out_movie + (size_t)row * 128 + sub * 4) = xv;
    }

#pragma unroll
    for (int t = 0; t < 4; ++t) {
        const int col = 16 * t + sub;
        const float bb = b1[col] + b2[col];
        const float br = brgcn[col];
        const f32x4 a = (t == 0) ? acc0 : (t == 1) ? acc1 : (t == 2) ? acc2 : acc3;
#pragma unroll
        for (int r = 0; r < 4; ++r) {
            const int row = rbase + 4 * grp + r;
            out_movie[(size_t)row * 128 + 64 + col] =
                a[r] + (float)cnt_m[row] * bb + br;
        }
    }
}

extern "C" void kernel_launch(void* const* d_in, const int* in_sizes, int n_in,
                              void* d_out, int out_size, void* d_ws, size_t ws_size,
                              hipStream_t stream)
{
    const float* user_x   = (const float*)d_in[0];
    const float* movie_x  = (const float*)d_in[1];
    const float* entity_x = (const float*)d_in[2];
    const int*   um       = (const int*)d_in[3];
    const int*   me       = (const int*)d_in[4];
    const float* W1       = (const float*)d_in[5];
    const float* b1       = (const float*)d_in[6];
    const float* W2       = (const float*)d_in[7];
    const float* b2       = (const float*)d_in[8];
    const float* Wrel     = (const float*)d_in[9];
    const float* Wroot    = (const float*)d_in[10];
    const float* brgcn    = (const float*)d_in[11];

    const int E_um = in_sizes[3] / 2;
    const int E_me = in_sizes[4] / 2;

    float* out_user  = (float*)d_out;                         // [NUSERS, 128]
    float* out_movie = out_user + (size_t)NUSERS * 128;       // [NMOVIES, 128]

    // Workspace layout (ints)
    int* cnt_all = (int*)d_ws;                 // [3][NROWS]  - zeroed
    int* sl_all  = cnt_all + NROWS3;           // [3][NROWS]
    int* bsum    = sl_all + NROWS3;            // [3][1024]
    int* bo_all  = bsum + 3 * 1024;            // [3][1024]
    int* w_umu   = bo_all + 3 * 1024;          // [E_um]
    int* w_umm   = w_umu + E_um;               // [E_um]
    int* w_me    = w_umm + E_um;               // [E_me]
    int* bk_u    = w_me + E_me;                // [E_um]
    int* bk_m    = bk_u + E_um;                // [E_um]
    int* bk_e    = bk_m + E_um;                // [E_me]
    uintptr_t bp = (uintptr_t)(bk_e + E_me);
    bp = (bp + 63) & ~(uintptr_t)63;
    unsigned short* BH = (unsigned short*)bp;  // [16384]
    unsigned short* BL = BH + 16384;           // [16384]

    int* cnt_u = cnt_all;
    int* cnt_m = cnt_all + NROWS;
    int* cnt_e = cnt_all + 2 * NROWS;

    const int n_tasks = 2 * E_um + E_me;
    const int task_blocks = (n_tasks + 255) / 256;

    // Zero the histogram tables (2.4 MB).
    hipMemsetAsync(cnt_all, 0, NROWS3 * sizeof(int), stream);

    bsplit_kernel<<<64, 256, 0, stream>>>(W1, W2, Wrel, Wroot, BH, BL);
    hist_kernel<<<task_blocks, 256, 0, stream>>>(um, me, cnt_u, cnt_m, cnt_e,
                                                 w_umu, w_umm, w_me, E_um, E_me);
    scan_blocks_kernel<<<3 * NBLK, 256, 0, stream>>>(cnt_all, sl_all, bsum);
    scan_tops_kernel<<<1, 1024, 0, stream>>>(bsum, bo_all);
    scatter_kernel<<<task_blocks, 256, 0, stream>>>(um, me, sl_all, bo_all,
                                                    w_umu, w_umm, w_me,
                                                    bk_u, bk_m, bk_e, E_um, E_me);

    // Gather phases (stream-sequential so each side's x-table stays L3-hot).
    gather_kernel<<<2048, 256, 0, stream>>>(bk_e, entity_x, cnt_e,
                                            sl_all + 2 * NROWS, bo_all + 2048,
                                            out_movie, 0, NMOVIES);
    gather_kernel<<<2048, 256, 0, stream>>>(bk_m, movie_x, cnt_m,
                                            sl_all + NROWS, bo_all + 1024,
                                            out_movie, 64, NMOVIES);
    gather_kernel<<<2048, 256, 0, stream>>>(bk_u, user_x, cnt_u,
                                            sl_all, bo_all,
                                            out_user, 64, NUSERS);

    finalize_user_mfma<<<NUSERS / 64, 256, 0, stream>>>(
        user_x, cnt_u, b1, b2, BH, BL, out_user);
    finalize_movie_mfma<<<NMOVIES / 64, 256, 0, stream>>>(
        movie_x, entity_x, cnt_m, cnt_e, b1, b2, brgcn, BH, BL, out_movie);
}